// Round 5
// baseline (122.531 us; speedup 1.0000x reference)
//
#include <hip/hip_runtime.h>

// NeRF volume compositing, MI355X — single fused kernel.
// 2 rays per 64-lane wave (32 lanes/ray), 4 contiguous samples per lane.
// T before a sample is the plain exclusive prefix product of (1-a):
// factors in (0,1], T monotone non-increasing, so "dead stays dead"
// truncation == thresholding the prefix product.
//
// rgb needs NO transpose: with 4 samples/lane, lane sl owns rgb floats
// [12*sl, 12*sl+12) which is three 16B-aligned float4s with a static
// register layout. Cross-lane work is 5 DPP ops (segmented scan) +
// 5 DPP + 1 ds_swizzle per reduced variable. total_samples is fused:
// per-block integer-valued float partials -> one atomicAdd per block
// (exact: all partial/total values are integers < 2^24 -> deterministic).

template<int CTRL, int RM>
__device__ __forceinline__ float dpp_mul1(float v) {
    // v *= dpp_move(v); inactive/out-of-row sources read old = 1.0f.
    float t = __int_as_float(__builtin_amdgcn_update_dpp(
        0x3f800000, __float_as_int(v), CTRL, RM, 0xF, false));
    return v * t;
}
template<int CTRL>
__device__ __forceinline__ float dpp_add0(float v) {
    float t = __int_as_float(__builtin_amdgcn_update_dpp(
        0, __float_as_int(v), CTRL, 0xF, 0xF, false));
    return v + t;
}
__device__ __forceinline__ float seg_reduce32(float v) {
    // Correct full 32-lane segment sum in lanes 0 and 32 (the readers).
    v = dpp_add0<0x101>(v);   // += lane+1 (row_shl:1)
    v = dpp_add0<0x102>(v);
    v = dpp_add0<0x104>(v);
    v = dpp_add0<0x108>(v);   // row leaders (0,16,32,48) hold row sums
    v += __int_as_float(__builtin_amdgcn_ds_swizzle(
            __float_as_int(v), 0x401F));   // xor-16 within 32-lane group
    return v;
}

typedef float f4a __attribute__((ext_vector_type(4), aligned(4)));

__global__ __launch_bounds__(256) void vr_main(
    const float* __restrict__ sigmas, const float* __restrict__ rgbs,
    const float* __restrict__ deltas, const float* __restrict__ ts,
    const int* __restrict__ rays_a, const float* __restrict__ thr_p,
    float* __restrict__ out, int R)
{
    __shared__ float blksum[4];

    const int wib  = (int)(threadIdx.x >> 6);
    const int wid  = (int)blockIdx.x * 4 + wib;
    const int lane = (int)(threadIdx.x & 63);
    const int half = lane >> 5;
    const int sl   = lane & 31;
    const int ray  = 2 * wid + half;
    const bool inR = ray < R;

    int ridx = 0, start = 0, count = 0;
    if (inR) {
        ridx  = rays_a[3 * ray + 0];
        start = rays_a[3 * ray + 1];
        count = rays_a[3 * ray + 2];
    }
    const float thr = thr_p[0];

    const bool ok = inR && (count == 128) && ((start & 3) == 0);
    const bool fastw = __all(ok);

    float fe[4], tv[4], rr[4], gg[4], bb[4];
    bool  v[4];

    if (fastw) {
        // All six 16B loads independent -> issued back-to-back (max MLP).
        const float4 sg4 = *(const float4*)(sigmas + start + 4 * sl);
        const float4 dt4 = *(const float4*)(deltas + start + 4 * sl);
        const float4 tt4 = *(const float4*)(ts     + start + 4 * sl);
        const float* rg = rgbs + 3 * ((size_t)start + 4 * sl);  // 48B-aligned
        const float4 c0 = *(const float4*)(rg + 0);
        const float4 c1 = *(const float4*)(rg + 4);
        const float4 c2 = *(const float4*)(rg + 8);

        fe[0] = __expf(-sg4.x * dt4.x);
        fe[1] = __expf(-sg4.y * dt4.y);
        fe[2] = __expf(-sg4.z * dt4.z);
        fe[3] = __expf(-sg4.w * dt4.w);
        tv[0] = tt4.x; tv[1] = tt4.y; tv[2] = tt4.z; tv[3] = tt4.w;
        rr[0] = c0.x; gg[0] = c0.y; bb[0] = c0.z;
        rr[1] = c0.w; gg[1] = c1.x; bb[1] = c1.y;
        rr[2] = c1.z; gg[2] = c1.w; bb[2] = c2.x;
        rr[3] = c2.y; gg[3] = c2.z; bb[3] = c2.w;
        v[0] = v[1] = v[2] = v[3] = true;
    } else {
        #pragma unroll
        for (int i = 0; i < 4; ++i) {
            const int s = 4 * sl + i;
            const bool vi = inR && (s < count);
            v[i] = vi;
            float sg = 0.f, dt = 0.f;
            tv[i] = 0.f; rr[i] = 0.f; gg[i] = 0.f; bb[i] = 0.f;
            if (vi) {
                sg = sigmas[start + s];
                dt = deltas[start + s];
                tv[i] = ts[start + s];
                const float* rg = rgbs + 3 * ((size_t)start + s);
                rr[i] = rg[0]; gg[i] = rg[1]; bb[i] = rg[2];
            }
            fe[i] = vi ? __expf(-sg * dt) : 1.f;
        }
    }

    // Per-lane product, then 32-lane segmented inclusive DPP scan.
    const float fprod = (fe[0] * fe[1]) * (fe[2] * fe[3]);
    float inc = fprod;
    inc = dpp_mul1<0x111, 0xF>(inc);   // row_shr:1
    inc = dpp_mul1<0x112, 0xF>(inc);   // row_shr:2
    inc = dpp_mul1<0x114, 0xF>(inc);   // row_shr:4
    inc = dpp_mul1<0x118, 0xF>(inc);   // row_shr:8
    inc = dpp_mul1<0x142, 0xA>(inc);   // row_bcast15 -> rows 1,3 only

    // Exclusive prefix = inclusive / own product (fprod >= exp(-~0.1)
    // for any in-range input chunk -> well-conditioned; sl==0 -> exactly 1).
    float T = inc / fprod;

    float w[4];
    float cnt = 0.f;
    #pragma unroll
    for (int i = 0; i < 4; ++i) {
        const bool alive = v[i] && (T > thr);
        const float Tn = T * fe[i];
        w[i] = alive ? (T - Tn) : 0.f;
        cnt += alive ? 1.f : 0.f;
        T = Tn;
    }

    // Per-sample weights: write-only stream -> nontemporal so it doesn't
    // evict cross-replay-resident inputs from L2/L3. Region base is odd
    // floats -> only 4B-aligned: use align(4) vector store.
    float* wsp = out + 1 + 5 * (size_t)R + (size_t)start + 4 * sl;
    if (fastw) {
        f4a wv; wv.x = w[0]; wv.y = w[1]; wv.z = w[2]; wv.w = w[3];
        __builtin_nontemporal_store(wv, (f4a*)wsp);
    } else {
        #pragma unroll
        for (int i = 0; i < 4; ++i) if (v[i]) wsp[i] = w[i];
    }

    // Per-ray reductions (segment sums land in lanes 0 and 32).
    float op  = (w[0] + w[1]) + (w[2] + w[3]);
    float dep = fmaf(w[0], tv[0], fmaf(w[1], tv[1], fmaf(w[2], tv[2], w[3] * tv[3])));
    float cr  = fmaf(w[0], rr[0], fmaf(w[1], rr[1], fmaf(w[2], rr[2], w[3] * rr[3])));
    float cg  = fmaf(w[0], gg[0], fmaf(w[1], gg[1], fmaf(w[2], gg[2], w[3] * gg[3])));
    float cb  = fmaf(w[0], bb[0], fmaf(w[1], bb[1], fmaf(w[2], bb[2], w[3] * bb[3])));

    op  = seg_reduce32(op);
    dep = seg_reduce32(dep);
    cr  = seg_reduce32(cr);
    cg  = seg_reduce32(cg);
    cb  = seg_reduce32(cb);

    if (sl == 0 && inR) {
        out[1 + ridx]             = op;
        out[1 + R + ridx]         = dep;
        out[1 + 2*R + 3*ridx + 0] = cr;
        out[1 + 2*R + 3*ridx + 1] = cg;
        out[1 + 2*R + 3*ridx + 2] = cb;
    }

    // Fused total_samples: full-wave sum, then one atomic per block.
    // All values are integer-valued floats, total <= 2^23 -> exact float
    // adds in any order -> deterministic across replays.
    cnt = seg_reduce32(cnt);
    cnt += __shfl_xor(cnt, 32, 64);
    if (lane == 0) blksum[wib] = cnt;
    __syncthreads();
    if (threadIdx.x == 0) {
        float t = (blksum[0] + blksum[1]) + (blksum[2] + blksum[3]);
        atomicAdd(&out[0], t);
    }
}

extern "C" void kernel_launch(void* const* d_in, const int* in_sizes, int n_in,
                              void* d_out, int out_size, void* d_ws, size_t ws_size,
                              hipStream_t stream) {
    const float* sigmas = (const float*)d_in[0];
    const float* rgbs   = (const float*)d_in[1];
    const float* deltas = (const float*)d_in[2];
    const float* ts     = (const float*)d_in[3];
    const int*   rays_a = (const int*)d_in[4];
    const float* thr    = (const float*)d_in[5];
    int R = in_sizes[4] / 3;
    float* out = (float*)d_out;

    // Seed for the fused atomic total (harness poisons d_out once before
    // timing and never re-poisons; every other out element is fully
    // overwritten by vr_main each replay).
    hipMemsetAsync(d_out, 0, 4, stream);

    int grid = (R + 7) / 8;  // 2 rays/wave, 4 waves/block -> 8 rays/block
    vr_main<<<grid, 256, 0, stream>>>(sigmas, rgbs, deltas, ts, rays_a, thr,
                                      out, R);
}

// Round 6
// 46.310 us; speedup vs baseline: 2.6459x; 2.6459x over previous
//
#include <hip/hip_runtime.h>

// NeRF volume compositing, MI355X.
// 2 rays per 64-lane wave (32 lanes/ray), 4 contiguous samples per lane.
// T before a sample is the plain exclusive prefix product of (1-a):
// factors in (0,1], T monotone non-increasing, so "dead stays dead"
// truncation == thresholding the prefix product.
//
// rgb needs NO transpose: with 4 samples/lane, lane sl owns rgb floats
// [12*sl, 12*sl+12) = three 16B-aligned float4s with a static register
// layout (48B-aligned base). Cross-lane: 5 DPP ops (segmented scan) and
// 5 DPP + 1 ds_swizzle per reduced variable.
//
// Round-5 lessons (both reverted here): no same-address per-block
// atomics (serialize at the cross-XCD coherence point); no nontemporal
// stores on misaligned streams (bypassing L2 defeats write-combining).

template<int CTRL, int RM>
__device__ __forceinline__ float dpp_mul1(float v) {
    // v *= dpp_move(v); inactive/out-of-row sources read old = 1.0f.
    float t = __int_as_float(__builtin_amdgcn_update_dpp(
        0x3f800000, __float_as_int(v), CTRL, RM, 0xF, false));
    return v * t;
}
template<int CTRL>
__device__ __forceinline__ float dpp_add0(float v) {
    float t = __int_as_float(__builtin_amdgcn_update_dpp(
        0, __float_as_int(v), CTRL, 0xF, 0xF, false));
    return v + t;
}
__device__ __forceinline__ float seg_reduce32(float v) {
    // Correct full 32-lane segment sum in lanes 0 and 32 (the readers).
    v = dpp_add0<0x101>(v);   // += lane+1 (row_shl:1)
    v = dpp_add0<0x102>(v);
    v = dpp_add0<0x104>(v);
    v = dpp_add0<0x108>(v);   // row leaders (0,16,32,48) hold row sums
    v += __int_as_float(__builtin_amdgcn_ds_swizzle(
            __float_as_int(v), 0x401F));   // xor-16 within 32-lane group
    return v;
}

typedef float f4a __attribute__((ext_vector_type(4), aligned(4)));

__global__ __launch_bounds__(256) void vr_main(
    const float* __restrict__ sigmas, const float* __restrict__ rgbs,
    const float* __restrict__ deltas, const float* __restrict__ ts,
    const int* __restrict__ rays_a, const float* __restrict__ thr_p,
    float* __restrict__ out, float* __restrict__ cnt_ws,
    int R, int use_ws)
{
    const int wib  = (int)(threadIdx.x >> 6);
    const int wid  = (int)blockIdx.x * 4 + wib;
    const int lane = (int)(threadIdx.x & 63);
    const int half = lane >> 5;
    const int sl   = lane & 31;
    const int ray  = 2 * wid + half;
    const bool inR = ray < R;

    int ridx = 0, start = 0, count = 0;
    if (inR) {
        ridx  = rays_a[3 * ray + 0];
        start = rays_a[3 * ray + 1];
        count = rays_a[3 * ray + 2];
    }
    const float thr = thr_p[0];

    const bool ok = inR && (count == 128) && ((start & 3) == 0);
    const bool fastw = __all(ok);

    float fe[4], tv[4], rr[4], gg[4], bb[4];
    bool  v[4];

    if (fastw) {
        // Six independent 16B loads, issued back-to-back (max MLP).
        const float4 sg4 = *(const float4*)(sigmas + start + 4 * sl);
        const float4 dt4 = *(const float4*)(deltas + start + 4 * sl);
        const float4 tt4 = *(const float4*)(ts     + start + 4 * sl);
        const float* rg = rgbs + 3 * ((size_t)start + 4 * sl);  // 48B-aligned
        const float4 c0 = *(const float4*)(rg + 0);
        const float4 c1 = *(const float4*)(rg + 4);
        const float4 c2 = *(const float4*)(rg + 8);

        fe[0] = __expf(-sg4.x * dt4.x);
        fe[1] = __expf(-sg4.y * dt4.y);
        fe[2] = __expf(-sg4.z * dt4.z);
        fe[3] = __expf(-sg4.w * dt4.w);
        tv[0] = tt4.x; tv[1] = tt4.y; tv[2] = tt4.z; tv[3] = tt4.w;
        rr[0] = c0.x; gg[0] = c0.y; bb[0] = c0.z;
        rr[1] = c0.w; gg[1] = c1.x; bb[1] = c1.y;
        rr[2] = c1.z; gg[2] = c1.w; bb[2] = c2.x;
        rr[3] = c2.y; gg[3] = c2.z; bb[3] = c2.w;
        v[0] = v[1] = v[2] = v[3] = true;
    } else {
        #pragma unroll
        for (int i = 0; i < 4; ++i) {
            const int s = 4 * sl + i;
            const bool vi = inR && (s < count);
            v[i] = vi;
            float sg = 0.f, dt = 0.f;
            tv[i] = 0.f; rr[i] = 0.f; gg[i] = 0.f; bb[i] = 0.f;
            if (vi) {
                sg = sigmas[start + s];
                dt = deltas[start + s];
                tv[i] = ts[start + s];
                const float* rg = rgbs + 3 * ((size_t)start + s);
                rr[i] = rg[0]; gg[i] = rg[1]; bb[i] = rg[2];
            }
            fe[i] = vi ? __expf(-sg * dt) : 1.f;
        }
    }

    // Per-lane product, then 32-lane segmented inclusive DPP scan.
    const float fprod = (fe[0] * fe[1]) * (fe[2] * fe[3]);
    float inc = fprod;
    inc = dpp_mul1<0x111, 0xF>(inc);   // row_shr:1
    inc = dpp_mul1<0x112, 0xF>(inc);   // row_shr:2
    inc = dpp_mul1<0x114, 0xF>(inc);   // row_shr:4
    inc = dpp_mul1<0x118, 0xF>(inc);   // row_shr:8
    inc = dpp_mul1<0x142, 0xA>(inc);   // row_bcast15 -> rows 1,3 only

    // Exclusive prefix = inclusive / own product (well-conditioned for
    // any in-range chunk; sl==0 -> exactly 1).
    float T = inc / fprod;

    float w[4];
    float cnt = 0.f;
    #pragma unroll
    for (int i = 0; i < 4; ++i) {
        const bool alive = v[i] && (T > thr);
        const float Tn = T * fe[i];
        w[i] = alive ? (T - Tn) : 0.f;
        cnt += alive ? 1.f : 0.f;
        T = Tn;
    }

    // Per-sample weights (ws region base is odd -> 4B-aligned wide store;
    // plain store: L2 write-combining handles the line-crossing).
    float* wsp = out + 1 + 5 * (size_t)R + (size_t)start + 4 * sl;
    if (fastw) {
        f4a wv; wv.x = w[0]; wv.y = w[1]; wv.z = w[2]; wv.w = w[3];
        *(f4a*)wsp = wv;
    } else {
        #pragma unroll
        for (int i = 0; i < 4; ++i) if (v[i]) wsp[i] = w[i];
    }

    // Per-ray reductions (segment sums land in lanes 0 and 32).
    float op  = (w[0] + w[1]) + (w[2] + w[3]);
    float dep = fmaf(w[0], tv[0], fmaf(w[1], tv[1], fmaf(w[2], tv[2], w[3] * tv[3])));
    float cr  = fmaf(w[0], rr[0], fmaf(w[1], rr[1], fmaf(w[2], rr[2], w[3] * rr[3])));
    float cg  = fmaf(w[0], gg[0], fmaf(w[1], gg[1], fmaf(w[2], gg[2], w[3] * gg[3])));
    float cb  = fmaf(w[0], bb[0], fmaf(w[1], bb[1], fmaf(w[2], bb[2], w[3] * bb[3])));

    op  = seg_reduce32(op);
    dep = seg_reduce32(dep);
    cr  = seg_reduce32(cr);
    cg  = seg_reduce32(cg);
    cb  = seg_reduce32(cb);
    cnt = seg_reduce32(cnt);

    if (sl == 0 && inR) {
        out[1 + ridx]             = op;
        out[1 + R + ridx]         = dep;
        out[1 + 2*R + 3*ridx + 0] = cr;
        out[1 + 2*R + 3*ridx + 1] = cg;
        out[1 + 2*R + 3*ridx + 2] = cb;
        if (use_ws) cnt_ws[ray] = cnt;
        else        atomicAdd(&out[0], cnt);
    }
}

// Single block: full sum of cnt_ws -> plain store to out[0] (overwrites
// poison deterministically every replay; no memset needed).
__global__ __launch_bounds__(1024) void vr_total(
    const float* __restrict__ cnt_ws, float* __restrict__ out, int R)
{
    __shared__ float sm[16];
    float s = 0.f;
    const int R4 = R & ~3;
    for (int i = (int)threadIdx.x * 4; i < R4; i += 4096) {
        const float4 c = *(const float4*)(cnt_ws + i);
        s += (c.x + c.y) + (c.z + c.w);
    }
    if (threadIdx.x == 0)
        for (int i = R4; i < R; ++i) s += cnt_ws[i];
    #pragma unroll
    for (int d = 32; d; d >>= 1) s += __shfl_xor(s, d, 64);
    if ((threadIdx.x & 63) == 0) sm[threadIdx.x >> 6] = s;
    __syncthreads();
    if (threadIdx.x == 0) {
        float t = 0.f;
        #pragma unroll
        for (int k = 0; k < 16; ++k) t += sm[k];
        out[0] = t;
    }
}

extern "C" void kernel_launch(void* const* d_in, const int* in_sizes, int n_in,
                              void* d_out, int out_size, void* d_ws, size_t ws_size,
                              hipStream_t stream) {
    const float* sigmas = (const float*)d_in[0];
    const float* rgbs   = (const float*)d_in[1];
    const float* deltas = (const float*)d_in[2];
    const float* ts     = (const float*)d_in[3];
    const int*   rays_a = (const int*)d_in[4];
    const float* thr    = (const float*)d_in[5];
    int R = in_sizes[4] / 3;
    float* out = (float*)d_out;
    float* cnt_ws = (float*)d_ws;

    int use_ws = (ws_size >= (size_t)R * sizeof(float)) ? 1 : 0;

    if (!use_ws)  // atomic fallback needs a zero seed for out[0]
        hipMemsetAsync(d_out, 0, 4, stream);

    int grid = (R + 7) / 8;  // 2 rays/wave, 4 waves/block -> 8 rays/block
    vr_main<<<grid, 256, 0, stream>>>(sigmas, rgbs, deltas, ts, rays_a, thr,
                                      out, cnt_ws, R, use_ws);
    if (use_ws)
        vr_total<<<1, 1024, 0, stream>>>(cnt_ws, out, R);
}